// Round 4
// baseline (294.030 us; speedup 1.0000x reference)
//
#include <hip/hip_runtime.h>
#include <hip/hip_bf16.h>
#include <math.h>

// ---------------------------------------------------------------------------
// CLSNet forward. B=8, C=128, H=W=128, Horg=Worg=512, NC=6, KP=8, NPROTO=48,
// PH=PW=4 (patches 32x32), 128 patches, 768 center rows.
// Outputs: pred[8,6,512,512] | proto_expand[8,48,128] | p2c[8,48,128,128] |
// distance_l2[8,48,16384] | proto_new[48,128]
// gt arrives as int32.
// kernE v6: fT LDS ELIMINATED. R2 model: v5 was LDS-pipe-bound (~37 µs/CU of
// LDS issue; VALU only ~8 µs). With lane map n0=(l&7)*4, all 64 lanes of an
// f wave-load fall in ONE 128B segment (8 kg-groups duplicate addresses ->
// coalescer merges) => direct global->reg f loads at coalesced cost, feats
// read once at HBM. F2 folded into main loop (k=48 row of red). LDS keeps
// only prot (broadcast) + reduce buffers: ~19 µs/CU ~= HBM floor.
// (R3 resubmit unchanged — acquisition timeout, never measured.)
// ---------------------------------------------------------------------------

#define E_M1 1.71828182845904523536f   // e - 1
#define INV_SQRT2 0.70710678118654752440f

typedef float v2f __attribute__((ext_vector_type(2)));

__device__ __forceinline__ float gelu_exact(float x) {
    return 0.5f * x * (1.f + erff(x * INV_SQRT2));
}
__device__ __forceinline__ v2f splat2(float x) { v2f r; r.x = x; r.y = x; return r; }

// ---------------------------------------------------------------------------
// kern0b: scrambled one-hot 6-bit mask per (b,P) directly from gt
// ---------------------------------------------------------------------------
__global__ __launch_bounds__(256) void kern0b(const int* __restrict__ gt,
                                              unsigned char* __restrict__ maskb) {
    int idx = blockIdx.x * 256 + threadIdx.x;          // 131072
    int b = idx >> 14, P = idx & 16383;
    const int* gb = gt + b * 262144;
    unsigned int m = 0;
    #pragma unroll
    for (int c = 0; c < 6; ++c) {
        int pos = c * 16384 + P;
        int hp = pos / 768;
        int rem = pos - hp * 768;
        int wp = rem / 6;
        int kp = rem - wp * 6;
        int g = gb[(4 * hp) * 512 + 4 * wp];
        int lab = (g == 6) ? 0 : g;
        if (lab == kp) m |= (1u << c);
    }
    maskb[idx] = (unsigned char)m;
}

// ---------------------------------------------------------------------------
// kernA1 v2: per-(patch,quarter) segmented channel sums. 512 blocks x 256
// threads: sub = t>>7 handles 4 of the 8 rows; LDS combine. part layout
// unchanged: part[pidx][7][128], pidx = patch*4+q.
// ---------------------------------------------------------------------------
__global__ __launch_bounds__(256) void kernA1(
    const float* __restrict__ feats, const unsigned char* __restrict__ maskb,
    float* __restrict__ part)
{
    __shared__ float accs[7][128];
    const int pidx = blockIdx.x;
    const int patch = pidx >> 2, q = pidx & 3;
    const int b = patch >> 4, pp = patch & 15, ihh = pp >> 2, iww = pp & 3;
    const int c = threadIdx.x & 127, sub = threadIdx.x >> 7;

    const int row0 = ihh * 32 + q * 8 + sub * 4;
    const float* fb = feats + (((long long)(b * 128 + c)) * 128 + row0) * 128 + iww * 32;
    const unsigned char* mb = maskb + b * 16384 + row0 * 128 + iww * 32;

    float s0 = 0.f, s1 = 0.f, s2 = 0.f, s3 = 0.f, s4 = 0.f, s5 = 0.f, sall = 0.f;
    for (int r = 0; r < 4; ++r) {
        const float4* row = (const float4*)(fb + r * 128);
        const unsigned int* mr = (const unsigned int*)(mb + r * 128);
        #pragma unroll
        for (int j = 0; j < 8; ++j) {
            float4 v = row[j];
            unsigned int u = mr[j];
            unsigned int b0 = u, b1 = u >> 8, b2 = u >> 16, b3 = u >> 24;
            s0 += ((b0 >> 0) & 1) ? v.x : 0.f;  s1 += ((b0 >> 1) & 1) ? v.x : 0.f;
            s2 += ((b0 >> 2) & 1) ? v.x : 0.f;  s3 += ((b0 >> 3) & 1) ? v.x : 0.f;
            s4 += ((b0 >> 4) & 1) ? v.x : 0.f;  s5 += ((b0 >> 5) & 1) ? v.x : 0.f;
            s0 += ((b1 >> 0) & 1) ? v.y : 0.f;  s1 += ((b1 >> 1) & 1) ? v.y : 0.f;
            s2 += ((b1 >> 2) & 1) ? v.y : 0.f;  s3 += ((b1 >> 3) & 1) ? v.y : 0.f;
            s4 += ((b1 >> 4) & 1) ? v.y : 0.f;  s5 += ((b1 >> 5) & 1) ? v.y : 0.f;
            s0 += ((b2 >> 0) & 1) ? v.z : 0.f;  s1 += ((b2 >> 1) & 1) ? v.z : 0.f;
            s2 += ((b2 >> 2) & 1) ? v.z : 0.f;  s3 += ((b2 >> 3) & 1) ? v.z : 0.f;
            s4 += ((b2 >> 4) & 1) ? v.z : 0.f;  s5 += ((b2 >> 5) & 1) ? v.z : 0.f;
            s0 += ((b3 >> 0) & 1) ? v.w : 0.f;  s1 += ((b3 >> 1) & 1) ? v.w : 0.f;
            s2 += ((b3 >> 2) & 1) ? v.w : 0.f;  s3 += ((b3 >> 3) & 1) ? v.w : 0.f;
            s4 += ((b3 >> 4) & 1) ? v.w : 0.f;  s5 += ((b3 >> 5) & 1) ? v.w : 0.f;
            sall += v.x + v.y + v.z + v.w;
        }
    }
    if (sub == 1) {
        accs[0][c] = s0; accs[1][c] = s1; accs[2][c] = s2; accs[3][c] = s3;
        accs[4][c] = s4; accs[5][c] = s5; accs[6][c] = sall;
    }
    __syncthreads();
    if (sub == 0) {
        float* po = part + pidx * 896;
        po[0 * 128 + c] = s0 + accs[0][c];
        po[1 * 128 + c] = s1 + accs[1][c];
        po[2 * 128 + c] = s2 + accs[2][c];
        po[3 * 128 + c] = s3 + accs[3][c];
        po[4 * 128 + c] = s4 + accs[4][c];
        po[5 * 128 + c] = s5 + accs[5][c];
        po[6 * 128 + c] = sall + accs[6][c];
    }
}

// ---------------------------------------------------------------------------
// kernA2: combine quarters -> ctx -> LN1 -> gelu -> centersT + fused argmin
// (nearest prototype, first-index ties). 128 blocks x 512 threads.
// ---------------------------------------------------------------------------
__global__ __launch_bounds__(512) void kernA2(
    const float* __restrict__ part, const unsigned char* __restrict__ maskb,
    const float* __restrict__ proto,
    const float* __restrict__ g1, const float* __restrict__ b1,
    float* __restrict__ centersT, int* __restrict__ nearest)
{
    __shared__ float ct[6][128];
    __shared__ int cnt[6];
    __shared__ float pl[48 * 129];     // proto, stride 129 -> 2-way banks (free)

    const int tid = threadIdx.x;
    const int p = blockIdx.x;                  // 0..127
    const int b = p >> 4, pp = p & 15, ihh = pp >> 2, iww = pp & 3;

    if (tid < 6) cnt[tid] = 0;
    for (int i = tid; i < 6144; i += 512)
        pl[(i >> 7) * 129 + (i & 127)] = proto[i];
    __syncthreads();

    // ---- counts from mask bytes (256 threads x 4 bytes, wave-reduced) ----
    if (tid < 256) {
        const unsigned char* mb = maskb + b * 16384 + ihh * 32 * 128 + iww * 32;
        int r = tid >> 3, jw = tid & 7;
        unsigned int u = *(const unsigned int*)(mb + r * 128 + jw * 4);
        #pragma unroll
        for (int k = 0; k < 6; ++k) {
            int cc = ((u >> k) & 1) + ((u >> (8 + k)) & 1) +
                     ((u >> (16 + k)) & 1) + ((u >> (24 + k)) & 1);
            #pragma unroll
            for (int m = 1; m < 64; m <<= 1) cc += __shfl_xor(cc, m, 64);
            if ((tid & 63) == 0 && cc) atomicAdd(&cnt[k], cc);
        }
    }
    __syncthreads();

    // ---- ctx closed form (768 items on 512 threads: STRIDED) ----
    const float* pb = part + (p * 4) * 896;
    for (int i = tid; i < 768; i += 512) {
        const int c = i & 127, k = i >> 7;
        float Sall = pb[6 * 128 + c] + pb[896 + 6 * 128 + c] +
                     pb[2 * 896 + 6 * 128 + c] + pb[3 * 896 + 6 * 128 + c];
        float Sk = pb[k * 128 + c] + pb[896 + k * 128 + c] +
                   pb[2 * 896 + k * 128 + c] + pb[3 * 896 + k * 128 + c];
        float Z = fmaf((float)cnt[k], E_M1, 1024.f);
        ct[k][c] = (Sall + E_M1 * Sk) / Z;
    }
    __syncthreads();

    // ---- LN over C + gelu -> centersT; fused nearest-proto argmin ----
    const int wv = tid >> 6, lane = tid & 63;
    if (wv < 6) {
        float x0 = ct[wv][lane], x1 = ct[wv][lane + 64];
        float s = x0 + x1;
        #pragma unroll
        for (int m = 1; m < 64; m <<= 1) s += __shfl_xor(s, m, 64);
        float mu = s * (1.f / 128.f);
        float d0 = x0 - mu, d1 = x1 - mu;
        float ss = d0 * d0 + d1 * d1;
        #pragma unroll
        for (int m = 1; m < 64; m <<= 1) ss += __shfl_xor(ss, m, 64);
        float inv = 1.f / sqrtf(ss * (1.f / 128.f) + 1e-6f);
        float y0 = d0 * inv * g1[lane] + b1[lane];
        float y1 = d1 * inv * g1[lane + 64] + b1[lane + 64];
        float z0 = gelu_exact(y0);
        float z1 = gelu_exact(y1);
        const int row = (b * 16 + pp) * 6 + wv;
        centersT[lane * 768 + row] = z0;
        centersT[(lane + 64) * 768 + row] = z1;

        // argmin over 48 protos (strict < : first index wins, matches jnp)
        float best = INFINITY; int bi = 0;
        for (int k = 0; k < 48; ++k) {
            float t0 = z0 - pl[k * 129 + lane];
            float t1 = z1 - pl[k * 129 + 64 + lane];
            float sd = fmaf(t0, t0, t1 * t1);
            #pragma unroll
            for (int m = 1; m < 64; m <<= 1) sd += __shfl_xor(sd, m, 64);
            if (sd < best) { best = sd; bi = k; }
        }
        if (lane == 0) nearest[row] = bi;
    }
}

// ---------------------------------------------------------------------------
// kernD: momentum scan (parallel over k, ordered predicated loop) + pn2
// ---------------------------------------------------------------------------
__global__ __launch_bounds__(128) void kernD(
    const float* __restrict__ proto0, const int* __restrict__ nearest,
    const float* __restrict__ centersT,
    float* __restrict__ proto_new, float* __restrict__ pn2,
    float* __restrict__ out_expand, float* __restrict__ out_proto)
{
    __shared__ int nl[768];
    __shared__ float wred[2];
    const int k = blockIdx.x, c = threadIdx.x;
    for (int i = c; i < 768; i += 128) nl[i] = nearest[i];
    __syncthreads();
    float p = proto0[k * 128 + c];
    const float OM = (float)(1.0 - 0.999);
    const float* col = centersT + c * 768;
    #pragma unroll 4
    for (int i = 0; i < 768; i += 4) {
        float4 v = *(const float4*)(col + i);
        if (nl[i + 0] == k) p = 0.999f * p + OM * v.x;
        if (nl[i + 1] == k) p = 0.999f * p + OM * v.y;
        if (nl[i + 2] == k) p = 0.999f * p + OM * v.z;
        if (nl[i + 3] == k) p = 0.999f * p + OM * v.w;
    }
    proto_new[k * 128 + c] = p;
    out_proto[k * 128 + c] = p;
    #pragma unroll
    for (int b = 0; b < 8; ++b) out_expand[(b * 48 + k) * 128 + c] = p;
    float sq = p * p;
    #pragma unroll
    for (int m = 1; m < 64; m <<= 1) sq += __shfl_xor(sq, m, 64);
    if ((c & 63) == 0) wred[c >> 6] = sq;
    __syncthreads();
    if (c == 0) pn2[k] = wred[0] + wred[1];
}

// ---------------------------------------------------------------------------
// kernE v6: 512 threads, 8 waves = (nh 2) x (cw 4); lane = (ng 8) x (kg 8)
// -> 4n x 6k x 32c per thread. f loads DIRECT global->reg (1 segment/instr:
// kg-groups duplicate addresses). prot in LDS (broadcast reads). F2 folded
// into main loop, spilled as red row k=48. red[4][49][66] aliases prot.
// grid (256,8) x 512. LDS 65056 B -> 2 blocks/CU, 16 waves/CU.
// ---------------------------------------------------------------------------
__global__ __launch_bounds__(512, 4) void kernE(
    const float* __restrict__ feats, const float* __restrict__ proto_new,
    const float* __restrict__ pn2g,
    const float* __restrict__ g2, const float* __restrict__ b2,
    float* __restrict__ out_sim, float* __restrict__ out_dist,
    float* __restrict__ pred_small)
{
    __shared__ float smem[16264];
    float* prot = smem;            // [48][132] 6336 f (dead after main loop)
    float* red  = smem;            // [4][49][66] = 12936 f (aliases prot)
    float* dst  = smem + 12936;    // [64][49] 3136 f
    float* F2   = smem + 16072;    // [64]
    float* muv  = smem + 16136;    // [64]
    float* invv = smem + 16200;    // [64]
    float* lnA  = smem;            // [4][64] (red dead by LN phase)
    float* lnB  = smem + 256;      // [4][64]

    const int t = threadIdx.x;
    const int b = blockIdx.y;
    const int nbase = blockIdx.x * 64;

    // ---- stage prot (float4) ----
    for (int i4 = t; i4 < 1536; i4 += 512) {
        float4 v = ((const float4*)proto_new)[i4];
        *(float4*)&prot[(i4 >> 5) * 132 + (i4 & 31) * 4] = v;
    }
    __syncthreads();

    // ---- main loop: wave (nh, cw); lane = (ng, kg) ----
    const int w = t >> 6, l = t & 63;
    const int cw = w & 3, nh = w >> 2;
    const int n0 = nh * 32 + (l & 7) * 4;   // 4 n per lane
    const int k0 = (l >> 3) * 6;            // 6 k per lane
    const int cbase = cw * 32;

    // per-thread f base: feats[b][cbase][nbase + n0]
    const float* fb = feats + (((long long)b) << 21) + (cbase << 14) + nbase + n0;

    v2f acc[6][2];
    #pragma unroll
    for (int j = 0; j < 6; ++j) { acc[j][0] = splat2(0.f); acc[j][1] = splat2(0.f); }
    v2f aF0 = splat2(0.f), aF1 = splat2(0.f);   // f^2 partial (this cw's 32 c)

    #pragma unroll
    for (int cq = 0; cq < 8; ++cq) {
        const int cb = cbase + cq * 4;
        v2f f[4][2];
        #pragma unroll
        for (int ch = 0; ch < 4; ++ch) {
            float4 a = *(const float4*)(fb + ((cq * 4 + ch) << 14));
            f[ch][0] = *(v2f*)&a.x; f[ch][1] = *(v2f*)&a.z;
        }
        #pragma unroll
        for (int j = 0; j < 6; ++j) {
            float4 pv = *(const float4*)&prot[(k0 + j) * 132 + cb];
            v2f px = splat2(pv.x), py = splat2(pv.y), pz = splat2(pv.z), pw = splat2(pv.w);
            #pragma unroll
            for (int h = 0; h < 2; ++h) {
                acc[j][h] = __builtin_elementwise_fma(f[0][h], px,
                            __builtin_elementwise_fma(f[1][h], py,
                            __builtin_elementwise_fma(f[2][h], pz,
                            __builtin_elementwise_fma(f[3][h], pw, acc[j][h]))));
            }
        }
        aF0 = __builtin_elementwise_fma(f[0][0], f[0][0],
              __builtin_elementwise_fma(f[1][0], f[1][0],
              __builtin_elementwise_fma(f[2][0], f[2][0],
              __builtin_elementwise_fma(f[3][0], f[3][0], aF0))));
        aF1 = __builtin_elementwise_fma(f[0][1], f[0][1],
              __builtin_elementwise_fma(f[1][1], f[1][1],
              __builtin_elementwise_fma(f[2][1], f[2][1],
              __builtin_elementwise_fma(f[3][1], f[3][1], aF1))));
    }
    __syncthreads();   // prot dead from here; region becomes red

    // ---- spill partials: red[cw][k][66-stride n]; k=48 row holds f^2 ----
    #pragma unroll
    for (int j = 0; j < 6; ++j) {
        *(v2f*)&red[cw * 3234 + (k0 + j) * 66 + n0]     = acc[j][0];
        *(v2f*)&red[cw * 3234 + (k0 + j) * 66 + n0 + 2] = acc[j][1];
    }
    if (l < 8) {   // kg==0 lanes: one copy of the f^2 partial per (cw, nh)
        *(v2f*)&red[cw * 3234 + 3168 + n0]     = aF0;
        *(v2f*)&red[cw * 3234 + 3168 + n0 + 2] = aF1;
    }
    __syncthreads();

    if (t < 64)   // F2[n] = sum over 4 cw partials
        F2[t] = ((red[3168 + t] + red[3234 + 3168 + t]) +
                 red[2 * 3234 + 3168 + t]) + red[3 * 3234 + 3168 + t];
    __syncthreads();

    // ---- combine 4 c-partials; 768 = (k, n-quad) cells on 512 threads ----
    for (int cell = t; cell < 768; cell += 512) {
        const int k = cell >> 4, n4 = (cell & 15) * 4;
        v2f lo = splat2(0.f), hi = splat2(0.f);
        #pragma unroll
        for (int ww = 0; ww < 4; ++ww) {
            lo += *(const v2f*)&red[ww * 3234 + k * 66 + n4];
            hi += *(const v2f*)&red[ww * 3234 + k * 66 + n4 + 2];
        }
        float pk = pn2g[k];
        float d0 = sqrtf(fmaxf(F2[n4 + 0] + pk - 2.f * lo.x, 0.f));
        float d1 = sqrtf(fmaxf(F2[n4 + 1] + pk - 2.f * lo.y, 0.f));
        float d2 = sqrtf(fmaxf(F2[n4 + 2] + pk - 2.f * hi.x, 0.f));
        float d3 = sqrtf(fmaxf(F2[n4 + 3] + pk - 2.f * hi.y, 0.f));
        float4 dv; dv.x = d0; dv.y = d1; dv.z = d2; dv.w = d3;
        *(float4*)(out_dist + (((long long)(b * 48 + k)) << 14) + nbase + n4) = dv;
        dst[(n4 + 0) * 49 + k] = 1.f / (1.f + 2.f * d0);
        dst[(n4 + 1) * 49 + k] = 1.f / (1.f + 2.f * d1);
        dst[(n4 + 2) * 49 + k] = 1.f / (1.f + 2.f * d2);
        dst[(n4 + 3) * 49 + k] = 1.f / (1.f + 2.f * d3);
    }
    __syncthreads();   // red dead from here; region becomes lnA/lnB

    // ---- LN stats per n: 256-thread partials, then combine ----
    if (t < 256) {
        const int n = t & 63, q = t >> 6;
        float s1 = 0.f, s2 = 0.f;
        for (int k = q * 12; k < q * 12 + 12; ++k) {
            float x = dst[n * 49 + k];
            s1 += x; s2 = fmaf(x, x, s2);
        }
        lnA[q * 64 + n] = s1;
        lnB[q * 64 + n] = s2;
    }
    __syncthreads();
    if (t < 64) {
        float s1 = ((lnA[t] + lnA[64 + t]) + lnA[128 + t]) + lnA[192 + t];
        float s2 = ((lnB[t] + lnB[64 + t]) + lnB[128 + t]) + lnB[192 + t];
        float mu = s1 * (1.f / 48.f);
        float var = fmaxf(s2 * (1.f / 48.f) - mu * mu, 0.f);
        muv[t] = mu;
        invv[t] = 1.f / sqrtf(var + 1e-6f);
    }
    __syncthreads();

    // ---- epilogue: 384 = (c6, n) items on 512 threads ----
    if (t < 384) {
        const int c6 = t >> 6, n = t & 63, ng = nbase + n;
        float mu = muv[n], inv = invv[n];
        float pm = 0.f;
        #pragma unroll
        for (int kp = 0; kp < 8; ++kp) {
            int k = kp * 6 + c6;
            float y = (dst[n * 49 + k] - mu) * inv * g2[k] + b2[k];
            float z = gelu_exact(y);
            out_sim[(((long long)(b * 48 + k)) << 14) + ng] = z;
            pm = (kp == 0) ? z : fmaxf(pm, z);
        }
        pred_small[((b * 6 + c6) << 14) + ng] = pm;
    }
}

// ---------------------------------------------------------------------------
// kernF: half-pixel bilinear x4 upsample (8,6,128,128)->(8,6,512,512)
// ---------------------------------------------------------------------------
__global__ __launch_bounds__(256) void kernF(
    const float* __restrict__ ps, float* __restrict__ pred)
{
    int idx = blockIdx.x * 256 + threadIdx.x;    // 3,145,728
    int xq = idx & 127;
    int oy = (idx >> 7) & 511;
    int bc = idx >> 16;
    int qy = oy >> 2, ry = oy & 3;
    int y0 = qy + ((ry < 2) ? -1 : 0);
    float fy = (ry == 0) ? 0.625f : (ry == 1) ? 0.875f : (ry == 2) ? 0.125f : 0.375f;
    int y0c = max(y0, 0), y1c = min(y0 + 1, 127);
    const float* base = ps + bc * 16384;
    const float* rA = base + y0c * 128;
    const float* rB = base + y1c * 128;
    int xm = max(xq - 1, 0), xp = min(xq + 1, 127);
    float a0 = rA[xm], a1 = rA[xq], a2 = rA[xp];
    float c0 = rB[xm], c1 = rB[xq], c2 = rB[xp];
    float w0 = 1.f - fy;
    float gm = w0 * a0 + fy * c0;
    float gc = w0 * a1 + fy * c1;
    float gp = w0 * a2 + fy * c2;
    float4 o;
    o.x = 0.375f * gm + 0.625f * gc;
    o.y = 0.125f * gm + 0.875f * gc;
    o.z = 0.875f * gc + 0.125f * gp;
    o.w = 0.625f * gc + 0.375f * gp;
    *(float4*)(pred + ((long long)idx << 2)) = o;
}

// ---------------------------------------------------------------------------
extern "C" void kernel_launch(void* const* d_in, const int* in_sizes, int n_in,
                              void* d_out, int out_size, void* d_ws, size_t ws_size,
                              hipStream_t stream)
{
    const float* feats = (const float*)d_in[0];
    const int* gt = (const int*)d_in[1];
    const float* proto = (const float*)d_in[2];
    const float* g1 = (const float*)d_in[3];
    const float* b1 = (const float*)d_in[4];
    const float* g2 = (const float*)d_in[5];
    const float* b2 = (const float*)d_in[6];

    float* out = (float*)d_out;
    float* pred       = out;
    float* out_expand = out + 12582912;
    float* out_sim    = out + 12632064;
    float* out_dist   = out + 18923520;
    float* out_proto  = out + 25214976;

    float* ws = (float*)d_ws;
    float* centersT   = ws + 98304;             // 98,304 (slot 0 unused)
    float* proto_new  = ws + 196608;            // 6,144
    float* pn2        = ws + 202752;            // 64
    int*   nearest    = (int*)(ws + 202816);    // 768
    float* part       = ws + 203584;            // 512*896 = 458,752
    float* pred_small = ws + 203584;            // ALIASED: kernE writes after
                                                // kernA2's last read of part
    unsigned char* maskb = (unsigned char*)(ws + 990016); // 131,072 B

    kern0b<<<512, 256, 0, stream>>>(gt, maskb);
    kernA1<<<512, 256, 0, stream>>>(feats, maskb, part);
    kernA2<<<128, 512, 0, stream>>>(part, maskb, proto, g1, b1, centersT, nearest);
    kernD <<<48, 128, 0, stream>>>(proto, nearest, centersT, proto_new, pn2,
                                   out_expand, out_proto);
    kernE <<<dim3(256, 8), 512, 0, stream>>>(feats, proto_new, pn2, g2, b2,
                                             out_sim, out_dist, pred_small);
    kernF <<<12288, 256, 0, stream>>>(pred_small, pred);
}

// Round 7
// 258.704 us; speedup vs baseline: 1.1365x; 1.1365x over previous
//
#include <hip/hip_runtime.h>
#include <hip/hip_bf16.h>
#include <math.h>

// ---------------------------------------------------------------------------
// CLSNet forward. B=8, C=128, H=W=128, Horg=Worg=512, NC=6, KP=8, NPROTO=48,
// PH=PW=4 (patches 32x32), 128 patches, 768 center rows.
// Outputs: pred[8,6,512,512] | proto_expand[8,48,128] | p2c[8,48,128,128] |
// distance_l2[8,48,16384] | proto_new[48,128]
// gt arrives as int32.
// Base = R2-measured build (259.8 µs): kernE v5 (512 thr, 8 waves = 2nh x
// 4cw, fT+prot LDS, 64KB), kernA1 v2 (256 thr).
// Delta (ONE change, resubmitted — R5/R6 infra timeouts, never measured):
// kernE fT staging via global_load_lds 16B DMA — LDS dest is linear (byte
// off = idx*16 = wave base + lane*16, the DMA constraint), global src
// per-lane. prot keeps reg-staging (stride-132 rows are non-linear; DMA
// would misplace). Same bytes -> zero numeric risk.
// ---------------------------------------------------------------------------

#define E_M1 1.71828182845904523536f   // e - 1
#define INV_SQRT2 0.70710678118654752440f

typedef float v2f __attribute__((ext_vector_type(2)));

__device__ __forceinline__ float gelu_exact(float x) {
    return 0.5f * x * (1.f + erff(x * INV_SQRT2));
}
__device__ __forceinline__ v2f splat2(float x) { v2f r; r.x = x; r.y = x; return r; }

// async 16-B global -> LDS DMA (gfx950). LDS dest must be wave-uniform
// base + lane*16 at the issuing instruction — caller guarantees linearity.
__device__ __forceinline__ void gload16(const float* g, float* l) {
    __builtin_amdgcn_global_load_lds(
        (const __attribute__((address_space(1))) void*)g,
        (__attribute__((address_space(3))) void*)l, 16, 0, 0);
}

// ---------------------------------------------------------------------------
// kern0b: scrambled one-hot 6-bit mask per (b,P) directly from gt
// ---------------------------------------------------------------------------
__global__ __launch_bounds__(256) void kern0b(const int* __restrict__ gt,
                                              unsigned char* __restrict__ maskb) {
    int idx = blockIdx.x * 256 + threadIdx.x;          // 131072
    int b = idx >> 14, P = idx & 16383;
    const int* gb = gt + b * 262144;
    unsigned int m = 0;
    #pragma unroll
    for (int c = 0; c < 6; ++c) {
        int pos = c * 16384 + P;
        int hp = pos / 768;
        int rem = pos - hp * 768;
        int wp = rem / 6;
        int kp = rem - wp * 6;
        int g = gb[(4 * hp) * 512 + 4 * wp];
        int lab = (g == 6) ? 0 : g;
        if (lab == kp) m |= (1u << c);
    }
    maskb[idx] = (unsigned char)m;
}

// ---------------------------------------------------------------------------
// kernA1 v2: per-(patch,quarter) segmented channel sums. 512 blocks x 256
// threads: sub = t>>7 handles 4 of the 8 rows; LDS combine. part layout
// unchanged: part[pidx][7][128], pidx = patch*4+q.
// ---------------------------------------------------------------------------
__global__ __launch_bounds__(256) void kernA1(
    const float* __restrict__ feats, const unsigned char* __restrict__ maskb,
    float* __restrict__ part)
{
    __shared__ float accs[7][128];
    const int pidx = blockIdx.x;
    const int patch = pidx >> 2, q = pidx & 3;
    const int b = patch >> 4, pp = patch & 15, ihh = pp >> 2, iww = pp & 3;
    const int c = threadIdx.x & 127, sub = threadIdx.x >> 7;

    const int row0 = ihh * 32 + q * 8 + sub * 4;
    const float* fb = feats + (((long long)(b * 128 + c)) * 128 + row0) * 128 + iww * 32;
    const unsigned char* mb = maskb + b * 16384 + row0 * 128 + iww * 32;

    float s0 = 0.f, s1 = 0.f, s2 = 0.f, s3 = 0.f, s4 = 0.f, s5 = 0.f, sall = 0.f;
    for (int r = 0; r < 4; ++r) {
        const float4* row = (const float4*)(fb + r * 128);
        const unsigned int* mr = (const unsigned int*)(mb + r * 128);
        #pragma unroll
        for (int j = 0; j < 8; ++j) {
            float4 v = row[j];
            unsigned int u = mr[j];
            unsigned int b0 = u, b1 = u >> 8, b2 = u >> 16, b3 = u >> 24;
            s0 += ((b0 >> 0) & 1) ? v.x : 0.f;  s1 += ((b0 >> 1) & 1) ? v.x : 0.f;
            s2 += ((b0 >> 2) & 1) ? v.x : 0.f;  s3 += ((b0 >> 3) & 1) ? v.x : 0.f;
            s4 += ((b0 >> 4) & 1) ? v.x : 0.f;  s5 += ((b0 >> 5) & 1) ? v.x : 0.f;
            s0 += ((b1 >> 0) & 1) ? v.y : 0.f;  s1 += ((b1 >> 1) & 1) ? v.y : 0.f;
            s2 += ((b1 >> 2) & 1) ? v.y : 0.f;  s3 += ((b1 >> 3) & 1) ? v.y : 0.f;
            s4 += ((b1 >> 4) & 1) ? v.y : 0.f;  s5 += ((b1 >> 5) & 1) ? v.y : 0.f;
            s0 += ((b2 >> 0) & 1) ? v.z : 0.f;  s1 += ((b2 >> 1) & 1) ? v.z : 0.f;
            s2 += ((b2 >> 2) & 1) ? v.z : 0.f;  s3 += ((b2 >> 3) & 1) ? v.z : 0.f;
            s4 += ((b2 >> 4) & 1) ? v.z : 0.f;  s5 += ((b2 >> 5) & 1) ? v.z : 0.f;
            s0 += ((b3 >> 0) & 1) ? v.w : 0.f;  s1 += ((b3 >> 1) & 1) ? v.w : 0.f;
            s2 += ((b3 >> 2) & 1) ? v.w : 0.f;  s3 += ((b3 >> 3) & 1) ? v.w : 0.f;
            s4 += ((b3 >> 4) & 1) ? v.w : 0.f;  s5 += ((b3 >> 5) & 1) ? v.w : 0.f;
            sall += v.x + v.y + v.z + v.w;
        }
    }
    if (sub == 1) {
        accs[0][c] = s0; accs[1][c] = s1; accs[2][c] = s2; accs[3][c] = s3;
        accs[4][c] = s4; accs[5][c] = s5; accs[6][c] = sall;
    }
    __syncthreads();
    if (sub == 0) {
        float* po = part + pidx * 896;
        po[0 * 128 + c] = s0 + accs[0][c];
        po[1 * 128 + c] = s1 + accs[1][c];
        po[2 * 128 + c] = s2 + accs[2][c];
        po[3 * 128 + c] = s3 + accs[3][c];
        po[4 * 128 + c] = s4 + accs[4][c];
        po[5 * 128 + c] = s5 + accs[5][c];
        po[6 * 128 + c] = sall + accs[6][c];
    }
}

// ---------------------------------------------------------------------------
// kernA2: combine quarters -> ctx -> LN1 -> gelu -> centersT + fused argmin
// (nearest prototype, first-index ties). 128 blocks x 512 threads.
// ---------------------------------------------------------------------------
__global__ __launch_bounds__(512) void kernA2(
    const float* __restrict__ part, const unsigned char* __restrict__ maskb,
    const float* __restrict__ proto,
    const float* __restrict__ g1, const float* __restrict__ b1,
    float* __restrict__ centersT, int* __restrict__ nearest)
{
    __shared__ float ct[6][128];
    __shared__ int cnt[6];
    __shared__ float pl[48 * 129];     // proto, stride 129 -> 2-way banks (free)

    const int tid = threadIdx.x;
    const int p = blockIdx.x;                  // 0..127
    const int b = p >> 4, pp = p & 15, ihh = pp >> 2, iww = pp & 3;

    if (tid < 6) cnt[tid] = 0;
    for (int i = tid; i < 6144; i += 512)
        pl[(i >> 7) * 129 + (i & 127)] = proto[i];
    __syncthreads();

    // ---- counts from mask bytes (256 threads x 4 bytes, wave-reduced) ----
    if (tid < 256) {
        const unsigned char* mb = maskb + b * 16384 + ihh * 32 * 128 + iww * 32;
        int r = tid >> 3, jw = tid & 7;
        unsigned int u = *(const unsigned int*)(mb + r * 128 + jw * 4);
        #pragma unroll
        for (int k = 0; k < 6; ++k) {
            int cc = ((u >> k) & 1) + ((u >> (8 + k)) & 1) +
                     ((u >> (16 + k)) & 1) + ((u >> (24 + k)) & 1);
            #pragma unroll
            for (int m = 1; m < 64; m <<= 1) cc += __shfl_xor(cc, m, 64);
            if ((tid & 63) == 0 && cc) atomicAdd(&cnt[k], cc);
        }
    }
    __syncthreads();

    // ---- ctx closed form (768 items on 512 threads: STRIDED) ----
    const float* pb = part + (p * 4) * 896;
    for (int i = tid; i < 768; i += 512) {
        const int c = i & 127, k = i >> 7;
        float Sall = pb[6 * 128 + c] + pb[896 + 6 * 128 + c] +
                     pb[2 * 896 + 6 * 128 + c] + pb[3 * 896 + 6 * 128 + c];
        float Sk = pb[k * 128 + c] + pb[896 + k * 128 + c] +
                   pb[2 * 896 + k * 128 + c] + pb[3 * 896 + k * 128 + c];
        float Z = fmaf((float)cnt[k], E_M1, 1024.f);
        ct[k][c] = (Sall + E_M1 * Sk) / Z;
    }
    __syncthreads();

    // ---- LN over C + gelu -> centersT; fused nearest-proto argmin ----
    const int wv = tid >> 6, lane = tid & 63;
    if (wv < 6) {
        float x0 = ct[wv][lane], x1 = ct[wv][lane + 64];
        float s = x0 + x1;
        #pragma unroll
        for (int m = 1; m < 64; m <<= 1) s += __shfl_xor(s, m, 64);
        float mu = s * (1.f / 128.f);
        float d0 = x0 - mu, d1 = x1 - mu;
        float ss = d0 * d0 + d1 * d1;
        #pragma unroll
        for (int m = 1; m < 64; m <<= 1) ss += __shfl_xor(ss, m, 64);
        float inv = 1.f / sqrtf(ss * (1.f / 128.f) + 1e-6f);
        float y0 = d0 * inv * g1[lane] + b1[lane];
        float y1 = d1 * inv * g1[lane + 64] + b1[lane + 64];
        float z0 = gelu_exact(y0);
        float z1 = gelu_exact(y1);
        const int row = (b * 16 + pp) * 6 + wv;
        centersT[lane * 768 + row] = z0;
        centersT[(lane + 64) * 768 + row] = z1;

        // argmin over 48 protos (strict < : first index wins, matches jnp)
        float best = INFINITY; int bi = 0;
        for (int k = 0; k < 48; ++k) {
            float t0 = z0 - pl[k * 129 + lane];
            float t1 = z1 - pl[k * 129 + 64 + lane];
            float sd = fmaf(t0, t0, t1 * t1);
            #pragma unroll
            for (int m = 1; m < 64; m <<= 1) sd += __shfl_xor(sd, m, 64);
            if (sd < best) { best = sd; bi = k; }
        }
        if (lane == 0) nearest[row] = bi;
    }
}

// ---------------------------------------------------------------------------
// kernD: momentum scan (parallel over k, ordered predicated loop) + pn2
// ---------------------------------------------------------------------------
__global__ __launch_bounds__(128) void kernD(
    const float* __restrict__ proto0, const int* __restrict__ nearest,
    const float* __restrict__ centersT,
    float* __restrict__ proto_new, float* __restrict__ pn2,
    float* __restrict__ out_expand, float* __restrict__ out_proto)
{
    __shared__ int nl[768];
    __shared__ float wred[2];
    const int k = blockIdx.x, c = threadIdx.x;
    for (int i = c; i < 768; i += 128) nl[i] = nearest[i];
    __syncthreads();
    float p = proto0[k * 128 + c];
    const float OM = (float)(1.0 - 0.999);
    const float* col = centersT + c * 768;
    #pragma unroll 4
    for (int i = 0; i < 768; i += 4) {
        float4 v = *(const float4*)(col + i);
        if (nl[i + 0] == k) p = 0.999f * p + OM * v.x;
        if (nl[i + 1] == k) p = 0.999f * p + OM * v.y;
        if (nl[i + 2] == k) p = 0.999f * p + OM * v.z;
        if (nl[i + 3] == k) p = 0.999f * p + OM * v.w;
    }
    proto_new[k * 128 + c] = p;
    out_proto[k * 128 + c] = p;
    #pragma unroll
    for (int b = 0; b < 8; ++b) out_expand[(b * 48 + k) * 128 + c] = p;
    float sq = p * p;
    #pragma unroll
    for (int m = 1; m < 64; m <<= 1) sq += __shfl_xor(sq, m, 64);
    if ((c & 63) == 0) wred[c >> 6] = sq;
    __syncthreads();
    if (c == 0) pn2[k] = wred[0] + wred[1];
}

// ---------------------------------------------------------------------------
// kernE v5.1: v5 + fT staging via global_load_lds DMA. 512 threads, 8 waves
// = (nh 2) x (cw 4). Wave (nh,cw): 32 n x 48 k x 32 c. Lane = 8 ng x 8 kg
// -> 4n x 6k. Per cq: 4 fT + 6 prot b128 reads feed 48 pk_fma. Cross-cw
// reduce via red[4][48][66] (aliases dead fT+prot). grid (256,8) x 512.
// LDS 64000 B -> 2 blocks/CU, 16 waves/CU.
// ---------------------------------------------------------------------------
__global__ __launch_bounds__(512) void kernE(
    const float* __restrict__ feats, const float* __restrict__ proto_new,
    const float* __restrict__ pn2g,
    const float* __restrict__ g2, const float* __restrict__ b2,
    float* __restrict__ out_sim, float* __restrict__ out_dist,
    float* __restrict__ pred_small)
{
    __shared__ float smem[16000];
    float* fT   = smem;            // [128][64]   (dead after main loop)
    float* prot = smem + 8192;     // [48][132]   (dead after main loop)
    float* p4   = smem + 14528;    // [8][64]  F2 partials (F2 phase only)
    float* red  = smem;            // [4][48][66] (after main loop)
    float* dst  = smem + 12672;    // [64][49]    (combine phase on)
    float* lnA  = smem;            // [4][64]  LN partials (red dead by then)
    float* lnB  = smem + 256;      // [4][64]
    float* F2   = smem + 15808;    // [64]
    float* muv  = smem + 15872;    // [64]
    float* invv = smem + 15936;    // [64]

    const int t = threadIdx.x;
    const int b = blockIdx.y;
    const int nbase = blockIdx.x * 64;

    // ---- stage fT via 16B DMA (LDS byte off = idx*16 -> linear in lane) ----
    #pragma unroll
    for (int it = 0; it < 4; ++it) {
        int idx = it * 512 + t;              // 0..2047
        int c = idx >> 4, qd = idx & 15;
        gload16(feats + (((long long)(b * 128 + c)) << 14) + nbase + qd * 4,
                &fT[idx * 4]);
    }
    // ---- stage prot (register path; stride-132 rows are non-linear) ----
    for (int i4 = t; i4 < 1536; i4 += 512) {
        float4 v = ((const float4*)proto_new)[i4];
        *(float4*)&prot[(i4 >> 5) * 132 + (i4 & 31) * 4] = v;
    }
    __syncthreads();

    {   // F2[n] = sum_c f^2 (8 partials x 16 channels)
        int n = t & 63, cg = t >> 6;
        float s = 0.f;
        for (int c = cg * 16; c < cg * 16 + 16; ++c) { float x = fT[c * 64 + n]; s = fmaf(x, x, s); }
        p4[cg * 64 + n] = s;
    }
    __syncthreads();
    if (t < 64) {
        float s = 0.f;
        #pragma unroll
        for (int g = 0; g < 8; ++g) s += p4[g * 64 + t];
        F2[t] = s;          // read only after post-main barriers
    }

    // ---- main loop: wave (nh, cw); lane = (ng, kg) ----
    const int w = t >> 6, l = t & 63;
    const int cw = w & 3, nh = w >> 2;
    const int n0 = nh * 32 + (l & 7) * 4;   // 4 n per lane
    const int k0 = (l >> 3) * 6;            // 6 k per lane
    const int cbase = cw * 32;

    v2f acc[6][2];
    #pragma unroll
    for (int j = 0; j < 6; ++j) { acc[j][0] = splat2(0.f); acc[j][1] = splat2(0.f); }

    #pragma unroll
    for (int cq = 0; cq < 8; ++cq) {
        const int cb = cbase + cq * 4;
        v2f f[4][2];
        #pragma unroll
        for (int ch = 0; ch < 4; ++ch) {
            float4 a0 = *(const float4*)&fT[(cb + ch) * 64 + n0];
            f[ch][0] = *(v2f*)&a0.x; f[ch][1] = *(v2f*)&a0.z;
        }
        #pragma unroll
        for (int j = 0; j < 6; ++j) {
            float4 pv = *(const float4*)&prot[(k0 + j) * 132 + cb];
            v2f px = splat2(pv.x), py = splat2(pv.y), pz = splat2(pv.z), pw = splat2(pv.w);
            #pragma unroll
            for (int h = 0; h < 2; ++h) {
                acc[j][h] = __builtin_elementwise_fma(f[0][h], px,
                            __builtin_elementwise_fma(f[1][h], py,
                            __builtin_elementwise_fma(f[2][h], pz,
                            __builtin_elementwise_fma(f[3][h], pw, acc[j][h]))));
            }
        }
    }
    __syncthreads();   // fT & prot dead from here; region becomes red

    // ---- spill partials: red[cw][k][66-stride n]; nh halves disjoint ----
    #pragma unroll
    for (int j = 0; j < 6; ++j) {
        *(v2f*)&red[cw * 3168 + (k0 + j) * 66 + n0]     = acc[j][0];
        *(v2f*)&red[cw * 3168 + (k0 + j) * 66 + n0 + 2] = acc[j][1];
    }
    __syncthreads();

    // ---- combine 4 c-partials; 768 = (k, n-quad) cells on 512 threads ----
    for (int cell = t; cell < 768; cell += 512) {
        const int k = cell >> 4, n4 = (cell & 15) * 4;
        v2f lo = splat2(0.f), hi = splat2(0.f);
        #pragma unroll
        for (int ww = 0; ww < 4; ++ww) {
            lo += *(const v2f*)&red[ww * 3168 + k * 66 + n4];
            hi += *(const v2f*)&red[ww * 3168 + k * 66 + n4 + 2];
        }
        float pk = pn2g[k];
        float d0 = sqrtf(fmaxf(F2[n4 + 0] + pk - 2.f * lo.x, 0.f));
        float d1 = sqrtf(fmaxf(F2[n4 + 1] + pk - 2.f * lo.y, 0.f));
        float d2 = sqrtf(fmaxf(F2[n4 + 2] + pk - 2.f * hi.x, 0.f));
        float d3 = sqrtf(fmaxf(F2[n4 + 3] + pk - 2.f * hi.y, 0.f));
        float4 dv; dv.x = d0; dv.y = d1; dv.z = d2; dv.w = d3;
        *(float4*)(out_dist + (((long long)(b * 48 + k)) << 14) + nbase + n4) = dv;
        dst[(n4 + 0) * 49 + k] = 1.f / (1.f + 2.f * d0);
        dst[(n4 + 1) * 49 + k] = 1.f / (1.f + 2.f * d1);
        dst[(n4 + 2) * 49 + k] = 1.f / (1.f + 2.f * d2);
        dst[(n4 + 3) * 49 + k] = 1.f / (1.f + 2.f * d3);
    }
    __syncthreads();   // red dead from here; region becomes lnA/lnB

    // ---- LN stats per n: 256-thread partials, then combine ----
    if (t < 256) {
        const int n = t & 63, q = t >> 6;
        float s1 = 0.f, s2 = 0.f;
        for (int k = q * 12; k < q * 12 + 12; ++k) {
            float x = dst[n * 49 + k];
            s1 += x; s2 = fmaf(x, x, s2);
        }
        lnA[q * 64 + n] = s1;
        lnB[q * 64 + n] = s2;
    }
    __syncthreads();
    if (t < 64) {
        float s1 = ((lnA[t] + lnA[64 + t]) + lnA[128 + t]) + lnA[192 + t];
        float s2 = ((lnB[t] + lnB[64 + t]) + lnB[128 + t]) + lnB[192 + t];
        float mu = s1 * (1.f / 48.f);
        float var = fmaxf(s2 * (1.f / 48.f) - mu * mu, 0.f);
        muv[t] = mu;
        invv[t] = 1.f / sqrtf(var + 1e-6f);
    }
    __syncthreads();

    // ---- epilogue: 384 = (c6, n) items on 512 threads ----
    if (t < 384) {
        const int c6 = t >> 6, n = t & 63, ng = nbase + n;
        float mu = muv[n], inv = invv[n];
        float pm = 0.f;
        #pragma unroll
        for (int kp = 0; kp < 8; ++kp) {
            int k = kp * 6 + c6;
            float y = (dst[n * 49 + k] - mu) * inv * g2[k] + b2[k];
            float z = gelu_exact(y);
            out_sim[(((long long)(b * 48 + k)) << 14) + ng] = z;
            pm = (kp == 0) ? z : fmaxf(pm, z);
        }
        pred_small[((b * 6 + c6) << 14) + ng] = pm;
    }
}

// ---------------------------------------------------------------------------
// kernF: half-pixel bilinear x4 upsample (8,6,128,128)->(8,6,512,512)
// ---------------------------------------------------------------------------
__global__ __launch_bounds__(256) void kernF(
    const float* __restrict__ ps, float* __restrict__ pred)
{
    int idx = blockIdx.x * 256 + threadIdx.x;    // 3,145,728
    int xq = idx & 127;
    int oy = (idx >> 7) & 511;
    int bc = idx >> 16;
    int qy = oy >> 2, ry = oy & 3;
    int y0 = qy + ((ry < 2) ? -1 : 0);
    float fy = (ry == 0) ? 0.625f : (ry == 1) ? 0.875f : (ry == 2) ? 0.125f : 0.375f;
    int y0c = max(y0, 0), y1c = min(y0 + 1, 127);
    const float* base = ps + bc * 16384;
    const float* rA = base + y0c * 128;
    const float* rB = base + y1c * 128;
    int xm = max(xq - 1, 0), xp = min(xq + 1, 127);
    float a0 = rA[xm], a1 = rA[xq], a2 = rA[xp];
    float c0 = rB[xm], c1 = rB[xq], c2 = rB[xp];
    float w0 = 1.f - fy;
    float gm = w0 * a0 + fy * c0;
    float gc = w0 * a1 + fy * c1;
    float gp = w0 * a2 + fy * c2;
    float4 o;
    o.x = 0.375f * gm + 0.625f * gc;
    o.y = 0.125f * gm + 0.875f * gc;
    o.z = 0.875f * gc + 0.125f * gp;
    o.w = 0.625f * gc + 0.375f * gp;
    *(float4*)(pred + ((long long)idx << 2)) = o;
}

// ---------------------------------------------------------------------------
extern "C" void kernel_launch(void* const* d_in, const int* in_sizes, int n_in,
                              void* d_out, int out_size, void* d_ws, size_t ws_size,
                              hipStream_t stream)
{
    const float* feats = (const float*)d_in[0];
    const int* gt = (const int*)d_in[1];
    const float* proto = (const float*)d_in[2];
    const float* g1 = (const float*)d_in[3];
    const float* b1 = (const float*)d_in[4];
    const float* g2 = (const float*)d_in[5];
    const float* b2 = (const float*)d_in[6];

    float* out = (float*)d_out;
    float* pred       = out;
    float* out_expand = out + 12582912;
    float* out_sim    = out + 12632064;
    float* out_dist   = out + 18923520;
    float* out_proto  = out + 25214976;

    float* ws = (float*)d_ws;
    float* centersT   = ws + 98304;             // 98,304 (slot 0 unused)
    float* proto_new  = ws + 196608;            // 6,144
    float* pn2        = ws + 202752;            // 64
    int*   nearest    = (int*)(ws + 202816);    // 768
    float* part       = ws + 203584;            // 512*896 = 458,752
    float* pred_small = ws + 203584;            // ALIASED: kernE writes after
                                                // kernA2's last read of part
    unsigned char* maskb = (unsigned char*)(ws + 990016); // 131,072 B

    kern0b<<<512, 256, 0, stream>>>(gt, maskb);
    kernA1<<<512, 256, 0, stream>>>(feats, maskb, part);
    kernA2<<<128, 512, 0, stream>>>(part, maskb, proto, g1, b1, centersT, nearest);
    kernD <<<48, 128, 0, stream>>>(proto, nearest, centersT, proto_new, pn2,
                                   out_expand, out_proto);
    kernE <<<dim3(256, 8), 512, 0, stream>>>(feats, proto_new, pn2, g2, b2,
                                             out_sim, out_dist, pred_small);
    kernF<<<12288, 256, 0, stream>>>(pred_small, pred);
}